// Round 10
// baseline (347.832 us; speedup 1.0000x reference)
//
#include <hip/hip_runtime.h>

// Problem constants (B=16,H=32,W=32,D=256,K=8192)
constexpr int NROWS = 16384;   // B*H*W
constexpr int D     = 256;
constexpr int K     = 8192;

constexpr float DECAY = 0.99f;
constexpr float OMD   = 0.01f;   // 1 - DECAY
constexpr float EPSF  = 1e-5f;

// Output layout (flat fp32, concatenated in return order)
constexpr size_t OUT_Q    = 0;                          // quantize_st  : NROWS*D
constexpr size_t OUT_LOSS = (size_t)NROWS * D;          // latent_loss  : 1
constexpr size_t OUT_NE   = OUT_LOSS + 1;               // new_embed    : D*K
constexpr size_t OUT_NCS  = OUT_NE + (size_t)D * K;     // new_cluster  : K
constexpr size_t OUT_NEA  = OUT_NCS + K;                // new_embed_avg: D*K

// Workspace byte offsets
constexpr size_t WS_KEYS  = 0;                              // NROWS u64   (128 KB)
constexpr size_t WS_ENORM = WS_KEYS + (size_t)NROWS * 8;    // K f32       (32 KB)
constexpr size_t WS_XH    = ((WS_ENORM + (size_t)K * 4 + 4095) / 4096) * 4096; // 8MB
constexpr size_t WS_XL    = WS_XH + (size_t)NROWS * D * 2;          // 8MB
constexpr size_t WS_EHT   = WS_XL + (size_t)NROWS * D * 2;          // K*D bf16 (4MB)
constexpr size_t WS_ELT   = WS_EHT + (size_t)K * D * 2;             // 4MB
// acc_t[K][D] f32 (8MB) aliases WS_XH after the main kernel (xh dead by then)

typedef unsigned int u32;
typedef unsigned short u16;
typedef unsigned long long u64;
typedef __attribute__((ext_vector_type(8))) short bf16x8;
typedef __attribute__((ext_vector_type(16))) float f32x16;
typedef __attribute__((ext_vector_type(4))) u32 u32x4;
typedef __attribute__((ext_vector_type(2))) u32 u32x2;

__device__ __forceinline__ u16 f2bf(float f) {
    u32 u = __float_as_uint(f);
    u32 r = (u + 0x7FFFu + ((u >> 16) & 1u)) >> 16;   // RN-even
    return (u16)r;
}
__device__ __forceinline__ float bf2f(u16 h) {
    return __uint_as_float((u32)h << 16);
}

__device__ __forceinline__ void gl_lds16(const void* g, void* l) {
    __builtin_amdgcn_global_load_lds(
        (const __attribute__((address_space(1))) u32*)g,
        (__attribute__((address_space(3))) u32*)l, 16, 0, 0);
}

// ---------------------------------------------------------------------------
// PRE: one fused kernel, grid-sectioned by blockIdx.x (all 256-thread blocks):
//   [0,128)     transpose+split embed -> ehT/elT + enorm   (kBase = bid*64)
//   [128,144)   keys init to 0xFF (+ block 128 thread 0 zeroes loss_out)
//   [144,176)   ncs_out = 0.99*cluster_size
//   [176,4272)  split x -> xh/xl
__global__ void pre_kernel(const float* __restrict__ x,
                           const float* __restrict__ embed,
                           const float* __restrict__ cluster_size,
                           u16* __restrict__ xh, u16* __restrict__ xl,
                           u16* __restrict__ ehT, u16* __restrict__ elT,
                           float* __restrict__ enorm,
                           u64* __restrict__ keys,
                           float* __restrict__ ncs_out,
                           float* __restrict__ loss_out) {
    const int bid = blockIdx.x;
    const int t   = threadIdx.x;

    if (bid >= 176) {                       // ---- split x (4096 blocks) ----
        size_t g = (size_t)(bid - 176) * 256 + t;   // < NROWS*D/4
        float4 v = *(const float4*)&x[g * 4];
        u16 h0 = f2bf(v.x), h1 = f2bf(v.y), h2 = f2bf(v.z), h3 = f2bf(v.w);
        u16 l0 = f2bf(v.x - bf2f(h0)), l1 = f2bf(v.y - bf2f(h1));
        u16 l2 = f2bf(v.z - bf2f(h2)), l3 = f2bf(v.w - bf2f(h3));
        u32x2 hp, lp;
        hp.x = (u32)h0 | ((u32)h1 << 16); hp.y = (u32)h2 | ((u32)h3 << 16);
        lp.x = (u32)l0 | ((u32)l1 << 16); lp.y = (u32)l2 | ((u32)l3 << 16);
        ((u32x2*)xh)[g] = hp;
        ((u32x2*)xl)[g] = lp;
        return;
    }
    if (bid >= 144) {                       // ---- ncs init (32 blocks) ----
        int i = (bid - 144) * 256 + t;      // < K
        ncs_out[i] = DECAY * cluster_size[i];
        return;
    }
    if (bid >= 128) {                       // ---- keys init (16 blocks) ----
        int idx = (bid - 128) * 256 + t;    // < 4096
        #pragma unroll
        for (int j = 0; j < 4; ++j) keys[j * 4096 + idx] = ~0ull;
        if (bid == 128 && t == 0) loss_out[0] = 0.f;
        return;
    }

    // ---- transpose + split embed + enorm (128 blocks) ----
    __shared__ float tile[64][68];
    const int kBase = bid * 64;
    const int dl = t >> 2;
    const int kl = t >> 2;
    const int qq = t & 3;
    float nacc = 0.f;

    for (int dBase = 0; dBase < D; dBase += 64) {
        #pragma unroll
        for (int i = 0; i < 4; ++i) {
            int kk = qq * 16 + i * 4;
            float4 v = *(const float4*)&embed[(size_t)(dBase + dl) * K + kBase + kk];
            tile[dl][kk + 0] = v.x; tile[dl][kk + 1] = v.y;
            tile[dl][kk + 2] = v.z; tile[dl][kk + 3] = v.w;
        }
        __syncthreads();
        u32 hp[8], lp[8];
        float s = 0.f;
        #pragma unroll
        for (int j = 0; j < 16; ++j) {
            float f = tile[qq * 16 + j][kl];
            s = fmaf(f, f, s);
            u16 hb = f2bf(f);
            u16 lb = f2bf(f - bf2f(hb));
            if (j & 1) { hp[j >> 1] |= (u32)hb << 16; lp[j >> 1] |= (u32)lb << 16; }
            else       { hp[j >> 1]  = hb;            lp[j >> 1]  = lb; }
        }
        s += __shfl_down(s, 1);
        s += __shfl_down(s, 2);
        if (qq == 0) nacc += s;

        size_t o = ((size_t)(kBase + kl) * D + dBase + qq * 16) >> 1;   // uint index
        u32x4 a, b;
        a.x = hp[0]; a.y = hp[1]; a.z = hp[2]; a.w = hp[3];
        b.x = hp[4]; b.y = hp[5]; b.z = hp[6]; b.w = hp[7];
        *(u32x4*)&((u32*)ehT)[o]     = a;
        *(u32x4*)&((u32*)ehT)[o + 4] = b;
        a.x = lp[0]; a.y = lp[1]; a.z = lp[2]; a.w = lp[3];
        b.x = lp[4]; b.y = lp[5]; b.z = lp[6]; b.w = lp[7];
        *(u32x4*)&((u32*)elT)[o]     = a;
        *(u32x4*)&((u32*)elT)[o + 4] = b;
        __syncthreads();
    }
    if (qq == 0) enorm[kBase + kl] = nacc;
}

// ---------------------------------------------------------------------------
// K-MAIN v10: v6's verified 4-phase barrier skeleton (barriers & staging
// placement byte-identical), with two contained changes:
//  (1) MFMA shape -> 32x32x16 bf16 (1.148x issue rate, half the instrs).
//      A/B frag: row/col = lane&31, k = 8*(lane>>5); C/D verified m74/m101.
//  (2) B-frag register double-buffer: phase p issues ds_read B[p+1], waits
//      counted lgkmcnt(4) (B[p+1] stays pending), MFMAs B[p]. Every early
//      read still completes before the same barrier that protected v6's
//      read of that region -> provably race-free.
// score(r,k) = enorm[k] - 2*(xh.eh + xh.el + xl.eh)
__global__ __launch_bounds__(512, 2) void dist_argmin_mfma(
        const u16* __restrict__ xh, const u16* __restrict__ xl,
        const u16* __restrict__ ehT, const u16* __restrict__ elT,
        const float* __restrict__ enorm,
        u64* __restrict__ keys) {
    __shared__ u16 lds[2][32768];   // 2 x 64KB

    const int tid  = threadIdx.x;
    const int lane = tid & 63;
    const int wave = tid >> 6;       // 0..7
    const int wm   = wave >> 1;      // row wave 0..3  (64 rows each)
    const int wn   = wave & 1;       // col wave 0..1  (128 cols each)
    const int c5   = lane & 31;      // row/col within a 32-tile
    const int hi   = lane >> 5;      // k-half selector
    const int rowBase = blockIdx.y * 256;
    const int colBase = blockIdx.x * 256;

    f32x16 acc[2][4];
    #pragma unroll
    for (int i = 0; i < 2; ++i)
        #pragma unroll
        for (int j = 0; j < 4; ++j) acc[i][j] = (f32x16)0.f;

    // ---- staging geometry (write side) — unchanged from v6 ----
    const int chunk8 = (((tid & 3) ^ ((tid >> 3) & 3)) * 8);
    const int arow   = tid >> 2;                 // 0..127
    const size_t a0 = (size_t)(rowBase + arow) * D + chunk8;
    const size_t a1 = (size_t)(rowBase + 128 + arow) * D + chunk8;
    const int bmat   = tid >> 8;                 // 0: eh, 1: el
    const int qrow   = (tid & 255) >> 2;         // 0..63
    const int bcol0  = (qrow < 32) ? qrow : (96 + qrow);   // + q*32
    const size_t bq0 = (size_t)(colBase + bcol0) * D + chunk8;
    const u16* bsrc  = bmat ? elT : ehT;

    #define ST_XH0(buf, ks) gl_lds16(&xh[a0 + (ks) * 32], &lds[buf][tid * 8])
    #define ST_XH1(buf, ks) gl_lds16(&xh[a1 + (ks) * 32], &lds[buf][4096 + tid * 8])
    #define ST_XL0(buf, ks) gl_lds16(&xl[a0 + (ks) * 32], &lds[buf][8192 + tid * 8])
    #define ST_XL1(buf, ks) gl_lds16(&xl[a1 + (ks) * 32], &lds[buf][12288 + tid * 8])
    #define ST_B(buf, ks, q) \
        gl_lds16(&bsrc[bq0 + (size_t)(q) * 32 * D + (ks) * 32], \
                 &lds[buf][16384 + (q) * 4096 + tid * 8])

    // ---- prologue: step0 (8 batches, oldest) + step1 first 6 ----
    ST_B(0, 0, 0); ST_XH0(0, 0); ST_B(0, 0, 1); ST_XH1(0, 0);
    ST_B(0, 0, 2); ST_XL0(0, 0); ST_B(0, 0, 3); ST_XL1(0, 0);
    ST_B(1, 1, 0); ST_XH0(1, 1); ST_B(1, 1, 1); ST_XH1(1, 1);
    ST_B(1, 1, 2); ST_XL0(1, 1);

    // ---- read-side fragments (32x32x16: row=lane&31, k-chunk = s*2+hi) ----
    bf16x8 fah[2][2], fal[2][2];       // [row-tile i][k-slice s]
    bf16x8 fbhA[2], fblA[2], fbhB[2], fblB[2];   // B double buffer, [s]

    #define RD_A(Lp)                                                             \
        do { _Pragma("unroll") for (int i_ = 0; i_ < 2; ++i_) {                  \
            _Pragma("unroll") for (int s_ = 0; s_ < 2; ++s_) {                   \
                const int row_ = wm * 64 + i_ * 32 + c5;                         \
                const int ck_  = ((s_ * 2 + hi) ^ ((row_ >> 1) & 3)) * 8;        \
                fah[i_][s_] = *(const bf16x8*)&(Lp)[row_ * 32 + ck_];            \
                fal[i_][s_] = *(const bf16x8*)&(Lp)[8192 + row_ * 32 + ck_];     \
        } } } while (0)

    #define RD_B(Lp, p, FH, FL)                                                  \
        do { _Pragma("unroll") for (int s_ = 0; s_ < 2; ++s_) {                   \
            const int br_ = wn * 32 + c5;                                         \
            const int ck_ = ((s_ * 2 + hi) ^ ((br_ >> 1) & 3)) * 8;               \
            (FH)[s_] = *(const bf16x8*)&(Lp)[16384 + (p) * 4096 + br_ * 32 + ck_];        \
            (FL)[s_] = *(const bf16x8*)&(Lp)[16384 + (p) * 4096 + 2048 + br_ * 32 + ck_]; \
        } } while (0)

    // 12 MFMAs per phase; acc targets alternate i to space same-acc chains
    #define MFMA_PH(p, FH, FL)                                                    \
        do { _Pragma("unroll") for (int s_ = 0; s_ < 2; ++s_) {                   \
            acc[0][p] = __builtin_amdgcn_mfma_f32_32x32x16_bf16(fah[0][s_], (FH)[s_], acc[0][p], 0, 0, 0); \
            acc[1][p] = __builtin_amdgcn_mfma_f32_32x32x16_bf16(fah[1][s_], (FH)[s_], acc[1][p], 0, 0, 0); \
            acc[0][p] = __builtin_amdgcn_mfma_f32_32x32x16_bf16(fah[0][s_], (FL)[s_], acc[0][p], 0, 0, 0); \
            acc[1][p] = __builtin_amdgcn_mfma_f32_32x32x16_bf16(fah[1][s_], (FL)[s_], acc[1][p], 0, 0, 0); \
            acc[0][p] = __builtin_amdgcn_mfma_f32_32x32x16_bf16(fal[0][s_], (FH)[s_], acc[0][p], 0, 0, 0); \
            acc[1][p] = __builtin_amdgcn_mfma_f32_32x32x16_bf16(fal[1][s_], (FH)[s_], acc[1][p], 0, 0, 0); \
        } } while (0)

    #define LGKM4() asm volatile("s_waitcnt lgkmcnt(4)" ::: "memory"); \
                    __builtin_amdgcn_sched_barrier(0)
    #define LGKM0() asm volatile("s_waitcnt lgkmcnt(0)" ::: "memory"); \
                    __builtin_amdgcn_sched_barrier(0)

    #pragma unroll
    for (int ks = 0; ks < 8; ++ks) {
        const int c = ks & 1;
        const u16* L = lds[c];

        // ---- phase 0: gate; read A + B0 + B1(early); stage; MFMA(B0) ----
        if (ks == 7) asm volatile("s_waitcnt vmcnt(0)" ::: "memory");
        else         asm volatile("s_waitcnt vmcnt(6)" ::: "memory");
        __builtin_amdgcn_s_barrier();           // all waves' step-ks loads landed
        __builtin_amdgcn_sched_barrier(0);

        RD_A(L);
        RD_B(L, 0, fbhA, fblA);
        RD_B(L, 1, fbhB, fblB);                 // early: stays pending
        if (ks <= 6) { ST_B(c ^ 1, ks + 1, 3); ST_XL1(c ^ 1, ks + 1); }
        LGKM4();                                // A+B0 done; B1 in flight
        __builtin_amdgcn_s_setprio(1);
        MFMA_PH(0, fbhA, fblA);
        __builtin_amdgcn_s_setprio(0);
        __builtin_amdgcn_s_barrier();           // ph0 reads done -> q0/A free
        __builtin_amdgcn_sched_barrier(0);

        // ---- phase 1: read B2(early); stage q0/XH0; MFMA(B1) ----
        RD_B(L, 2, fbhA, fblA);
        if (ks <= 5) { ST_B(c, ks + 2, 0); ST_XH0(c, ks + 2); }
        LGKM4();                                // B1 done; B2 in flight
        __builtin_amdgcn_s_setprio(1);
        MFMA_PH(1, fbhB, fblB);
        __builtin_amdgcn_s_setprio(0);
        __builtin_amdgcn_s_barrier();
        __builtin_amdgcn_sched_barrier(0);

        // ---- phase 2: read B3(early); stage q1/XH1; MFMA(B2) ----
        RD_B(L, 3, fbhB, fblB);
        if (ks <= 5) { ST_B(c, ks + 2, 1); ST_XH1(c, ks + 2); }
        LGKM4();                                // B2 done; B3 in flight
        __builtin_amdgcn_s_setprio(1);
        MFMA_PH(2, fbhA, fblA);
        __builtin_amdgcn_s_setprio(0);
        __builtin_amdgcn_s_barrier();
        __builtin_amdgcn_sched_barrier(0);

        // ---- phase 3: stage q2/XL0; MFMA(B3) ----
        if (ks <= 5) { ST_B(c, ks + 2, 2); ST_XL0(c, ks + 2); }
        LGKM0();                                // B3 done
        __builtin_amdgcn_s_setprio(1);
        MFMA_PH(3, fbhB, fblB);
        __builtin_amdgcn_s_setprio(0);
        __builtin_amdgcn_s_barrier();
        __builtin_amdgcn_sched_barrier(0);
    }
    #undef MFMA_PH
    #undef RD_A
    #undef RD_B
    #undef LGKM4
    #undef LGKM0
    #undef ST_XH0
    #undef ST_XH1
    #undef ST_XL0
    #undef ST_XL1
    #undef ST_B

    // ---- epilogue: argmin. 32x32 C/D: col=lane&31, row=(p&3)+8*(p>>2)+4*hi
    float en[4];
    #pragma unroll
    for (int j = 0; j < 4; ++j) en[j] = enorm[colBase + wn * 128 + j * 32 + c5];

    #pragma unroll
    for (int i = 0; i < 2; ++i) {
        #pragma unroll
        for (int p = 0; p < 16; ++p) {
            float best = __builtin_inff();
            int bk = 0;
            #pragma unroll
            for (int j = 0; j < 4; ++j) {
                float s = fmaf(-2.f, acc[i][j][p], en[j]);
                int ccol = colBase + wn * 128 + j * 32 + c5;
                if (s < best) { best = s; bk = ccol; }
            }
            u32 u = __float_as_uint(best);
            u ^= (u >> 31) ? 0xFFFFFFFFu : 0x80000000u;   // monotonic float->uint
            u64 key = ((u64)u << 32) | (u32)bk;
            #pragma unroll
            for (int m = 1; m < 32; m <<= 1) {            // reduce within 32-lane half
                u64 o = __shfl_xor(key, m);
                key = o < key ? o : key;
            }
            if (c5 == 0)
                atomicMin(&keys[rowBase + wm * 64 + i * 32 +
                                (p & 3) + 8 * (p >> 2) + 4 * hi], key);
        }
    }
}

// ---------------------------------------------------------------------------
// K4: fused postprocess — per row: quantize gather + q_out write + loss
// partial + EMA scatter into transposed acc_t[K][D] (coalesced atomics).
__global__ void postprocess_kernel(const float* __restrict__ x,
                                   const u16* __restrict__ ehT,
                                   const u16* __restrict__ elT,
                                   const u64* __restrict__ keys,
                                   float* __restrict__ q_out,
                                   float* __restrict__ loss_out,
                                   float* __restrict__ acc_t,
                                   float* __restrict__ ncs_out) {
    const int w    = threadIdx.x >> 6;
    const int lane = threadIdx.x & 63;
    const int r    = blockIdx.x * 4 + w;
    const u32 k = (u32)keys[r];

    float4 xv = *(const float4*)&x[(size_t)r * D + lane * 4];
    size_t uo = ((size_t)k * D >> 1) + lane * 2;
    u32x2 hp = *(const u32x2*)&((const u32*)ehT)[uo];
    u32x2 lp = *(const u32x2*)&((const u32*)elT)[uo];
    float q0 = __uint_as_float(hp.x << 16)         + __uint_as_float(lp.x << 16);
    float q1 = __uint_as_float(hp.x & 0xFFFF0000u) + __uint_as_float(lp.x & 0xFFFF0000u);
    float q2 = __uint_as_float(hp.y << 16)         + __uint_as_float(lp.y << 16);
    float q3 = __uint_as_float(hp.y & 0xFFFF0000u) + __uint_as_float(lp.y & 0xFFFF0000u);
    *(float4*)&q_out[(size_t)r * D + lane * 4] = make_float4(q0, q1, q2, q3);

    float* dst = &acc_t[(size_t)k * D + lane * 4];
    atomicAdd(dst + 0, xv.x);
    atomicAdd(dst + 1, xv.y);
    atomicAdd(dst + 2, xv.z);
    atomicAdd(dst + 3, xv.w);
    if (lane == 0) atomicAdd(&ncs_out[k], OMD);

    float d0 = q0 - xv.x, d1 = q1 - xv.y, d2 = q2 - xv.z, d3 = q3 - xv.w;
    float lsum = fmaf(d0, d0, fmaf(d1, d1, fmaf(d2, d2, d3 * d3)));
    #pragma unroll
    for (int off = 32; off > 0; off >>= 1) lsum += __shfl_down(lsum, off);
    __shared__ float wsum[4];
    if (lane == 0) wsum[w] = lsum;
    __syncthreads();
    if (threadIdx.x == 0) {
        float s = wsum[0] + wsum[1] + wsum[2] + wsum[3];
        atomicAdd(loss_out, s * (1.0f / ((float)NROWS * (float)D)));
    }
}

// K6: fused finalize — transpose acc_t[K][D] -> nea_out[D][K] combined with
// EMA (0.99*embed_avg + 0.01*acc) AND new_embed = nea/cs in one pass.
// n is re-derived per block from cluster_size (32KB, L2-resident).
__global__ void ema_finalize_kernel(const float* __restrict__ embed_avg,
                                    const float* __restrict__ acc_t,
                                    const float* __restrict__ ncs_out,
                                    const float* __restrict__ cluster_size,
                                    float* __restrict__ nea_out,
                                    float* __restrict__ ne_out) {
    __shared__ float tile[64][68];   // [k][d]
    __shared__ float wsums[4];
    const int kBase = blockIdx.x * 64;   // K/64 = 128
    const int dBase = blockIdx.y * 64;   // D/64 = 4
    const int t = threadIdx.x;

    // per-block cssum reduce (stride-256 coalesced)
    float cs_part = 0.f;
    #pragma unroll
    for (int j = 0; j < K / 256; ++j) cs_part += cluster_size[j * 256 + t];
    #pragma unroll
    for (int off = 32; off > 0; off >>= 1) cs_part += __shfl_down(cs_part, off);
    if ((t & 63) == 0) wsums[t >> 6] = cs_part;

    {
        const int kl = t >> 2, q = t & 3;
        #pragma unroll
        for (int i = 0; i < 4; ++i) {
            int dd = q * 16 + i * 4;
            float4 v = *(const float4*)&acc_t[(size_t)(kBase + kl) * D + dBase + dd];
            tile[kl][dd + 0] = v.x; tile[kl][dd + 1] = v.y;
            tile[kl][dd + 2] = v.z; tile[kl][dd + 3] = v.w;
        }
    }
    __syncthreads();
    const float cssum = wsums[0] + wsums[1] + wsums[2] + wsums[3];
    const float n = DECAY * cssum + OMD * (float)NROWS;
    const float inv_na = 1.0f / (n + (float)K * EPSF);
    const int dl = t >> 2, q = t & 3;
    #pragma unroll
    for (int i = 0; i < 4; ++i) {
        int kk = q * 16 + i * 4;
        size_t o = (size_t)(dBase + dl) * K + kBase + kk;
        float4 ea = *(const float4*)&embed_avg[o];
        float4 nea, ne;
        #pragma unroll
        for (int c = 0; c < 4; ++c) {
            float v  = DECAY * ((const float*)&ea)[c] + OMD * tile[kk + c][dl];
            float cs = (ncs_out[kBase + kk + c] + EPSF) * inv_na * n;
            ((float*)&nea)[c] = v;
            ((float*)&ne)[c]  = v / cs;
        }
        *(float4*)&nea_out[o] = nea;
        *(float4*)&ne_out[o]  = ne;
    }
}

// ---------------------------------------------------------------------------
extern "C" void kernel_launch(void* const* d_in, const int* in_sizes, int n_in,
                              void* d_out, int out_size, void* d_ws, size_t ws_size,
                              hipStream_t stream) {
    (void)in_sizes; (void)n_in; (void)out_size; (void)ws_size;
    const float* x            = (const float*)d_in[0];
    const float* embed        = (const float*)d_in[1];
    const float* cluster_size = (const float*)d_in[2];
    const float* embed_avg    = (const float*)d_in[3];
    float* out = (float*)d_out;

    char* ws = (char*)d_ws;
    u64*   keys  = (u64*)(ws + WS_KEYS);
    float* enorm = (float*)(ws + WS_ENORM);
    u16*   xh    = (u16*)(ws + WS_XH);
    u16*   xl    = (u16*)(ws + WS_XL);
    u16*   ehT   = (u16*)(ws + WS_EHT);
    u16*   elT   = (u16*)(ws + WS_ELT);
    float* acc_t = (float*)(ws + WS_XH);   // aliases xh: dead after main kernel

    float* q_out    = out + OUT_Q;
    float* loss_out = out + OUT_LOSS;
    float* ne_out   = out + OUT_NE;
    float* ncs_out  = out + OUT_NCS;
    float* nea_out  = out + OUT_NEA;

    // One fused pre-kernel: transpose/split/enorm + keys init + ncs init +
    // loss zero + x split.
    pre_kernel<<<dim3(176 + NROWS * D / 4 / 256), dim3(256), 0, stream>>>(
        x, embed, cluster_size, xh, xl, ehT, elT, enorm, keys, ncs_out, loss_out);

    dist_argmin_mfma<<<dim3(K / 256, NROWS / 256), dim3(512), 0, stream>>>(
        xh, xl, ehT, elT, enorm, keys);

    // xh is dead now; reuse it as the transposed EMA accumulator
    hipMemsetAsync(acc_t, 0, (size_t)K * D * 4, stream);
    postprocess_kernel<<<dim3(NROWS / 4), dim3(256), 0, stream>>>(
        x, ehT, elT, keys, q_out, loss_out, acc_t, ncs_out);
    ema_finalize_kernel<<<dim3(K / 64, D / 64), dim3(256), 0, stream>>>(
        embed_avg, acc_t, ncs_out, cluster_size, nea_out, ne_out);
}

// Round 11
// 298.523 us; speedup vs baseline: 1.1652x; 1.1652x over previous
//
#include <hip/hip_runtime.h>

// Problem constants (B=16,H=32,W=32,D=256,K=8192)
constexpr int NROWS = 16384;   // B*H*W
constexpr int D     = 256;
constexpr int K     = 8192;

constexpr float DECAY = 0.99f;
constexpr float OMD   = 0.01f;   // 1 - DECAY
constexpr float EPSF  = 1e-5f;

// Output layout (flat fp32, concatenated in return order)
constexpr size_t OUT_Q    = 0;                          // quantize_st  : NROWS*D
constexpr size_t OUT_LOSS = (size_t)NROWS * D;          // latent_loss  : 1
constexpr size_t OUT_NE   = OUT_LOSS + 1;               // new_embed    : D*K
constexpr size_t OUT_NCS  = OUT_NE + (size_t)D * K;     // new_cluster  : K
constexpr size_t OUT_NEA  = OUT_NCS + K;                // new_embed_avg: D*K

// Workspace byte offsets
constexpr size_t WS_KEYS  = 0;                              // NROWS u64   (128 KB)
constexpr size_t WS_ENORM = WS_KEYS + (size_t)NROWS * 8;    // K f32       (32 KB)
constexpr size_t WS_XH    = ((WS_ENORM + (size_t)K * 4 + 4095) / 4096) * 4096; // 8MB
constexpr size_t WS_XL    = WS_XH + (size_t)NROWS * D * 2;          // 8MB
constexpr size_t WS_EHT   = WS_XL + (size_t)NROWS * D * 2;          // K*D bf16 (4MB)
constexpr size_t WS_ELT   = WS_EHT + (size_t)K * D * 2;             // 4MB
// acc_t[K][D] f32 (8MB) aliases WS_XH after the main kernel (xh dead by then)

typedef unsigned int u32;
typedef unsigned short u16;
typedef unsigned long long u64;
typedef __attribute__((ext_vector_type(8))) short bf16x8;
typedef __attribute__((ext_vector_type(4))) float f32x4;
typedef __attribute__((ext_vector_type(4))) u32 u32x4;
typedef __attribute__((ext_vector_type(2))) u32 u32x2;

__device__ __forceinline__ u16 f2bf(float f) {
    u32 u = __float_as_uint(f);
    u32 r = (u + 0x7FFFu + ((u >> 16) & 1u)) >> 16;   // RN-even
    return (u16)r;
}
__device__ __forceinline__ float bf2f(u16 h) {
    return __uint_as_float((u32)h << 16);
}

__device__ __forceinline__ void gl_lds16(const void* g, void* l) {
    __builtin_amdgcn_global_load_lds(
        (const __attribute__((address_space(1))) u32*)g,
        (__attribute__((address_space(3))) u32*)l, 16, 0, 0);
}

// ---------------------------------------------------------------------------
// PRE: one fused kernel, grid-sectioned by blockIdx.x (all 256-thread blocks):
//   [0,128)     transpose+split embed -> ehT/elT + enorm   (kBase = bid*64)
//   [128,144)   keys init to 0xFF (+ block 128 thread 0 zeroes loss_out)
//   [144,176)   ncs_out = 0.99*cluster_size
//   [176,4272)  split x -> xh/xl
__global__ void pre_kernel(const float* __restrict__ x,
                           const float* __restrict__ embed,
                           const float* __restrict__ cluster_size,
                           u16* __restrict__ xh, u16* __restrict__ xl,
                           u16* __restrict__ ehT, u16* __restrict__ elT,
                           float* __restrict__ enorm,
                           u64* __restrict__ keys,
                           float* __restrict__ ncs_out,
                           float* __restrict__ loss_out) {
    const int bid = blockIdx.x;
    const int t   = threadIdx.x;

    if (bid >= 176) {                       // ---- split x (4096 blocks) ----
        size_t g = (size_t)(bid - 176) * 256 + t;   // < NROWS*D/4
        float4 v = *(const float4*)&x[g * 4];
        u16 h0 = f2bf(v.x), h1 = f2bf(v.y), h2 = f2bf(v.z), h3 = f2bf(v.w);
        u16 l0 = f2bf(v.x - bf2f(h0)), l1 = f2bf(v.y - bf2f(h1));
        u16 l2 = f2bf(v.z - bf2f(h2)), l3 = f2bf(v.w - bf2f(h3));
        u32x2 hp, lp;
        hp.x = (u32)h0 | ((u32)h1 << 16); hp.y = (u32)h2 | ((u32)h3 << 16);
        lp.x = (u32)l0 | ((u32)l1 << 16); lp.y = (u32)l2 | ((u32)l3 << 16);
        ((u32x2*)xh)[g] = hp;
        ((u32x2*)xl)[g] = lp;
        return;
    }
    if (bid >= 144) {                       // ---- ncs init (32 blocks) ----
        int i = (bid - 144) * 256 + t;      // < K
        ncs_out[i] = DECAY * cluster_size[i];
        return;
    }
    if (bid >= 128) {                       // ---- keys init (16 blocks) ----
        int idx = (bid - 128) * 256 + t;    // < 4096
        #pragma unroll
        for (int j = 0; j < 4; ++j) keys[j * 4096 + idx] = ~0ull;
        if (bid == 128 && t == 0) loss_out[0] = 0.f;
        return;
    }

    // ---- transpose + split embed + enorm (128 blocks) ----
    __shared__ float tile[64][68];
    const int kBase = bid * 64;
    const int dl = t >> 2;
    const int kl = t >> 2;
    const int qq = t & 3;
    float nacc = 0.f;

    for (int dBase = 0; dBase < D; dBase += 64) {
        #pragma unroll
        for (int i = 0; i < 4; ++i) {
            int kk = qq * 16 + i * 4;
            float4 v = *(const float4*)&embed[(size_t)(dBase + dl) * K + kBase + kk];
            tile[dl][kk + 0] = v.x; tile[dl][kk + 1] = v.y;
            tile[dl][kk + 2] = v.z; tile[dl][kk + 3] = v.w;
        }
        __syncthreads();
        u32 hp[8], lp[8];
        float s = 0.f;
        #pragma unroll
        for (int j = 0; j < 16; ++j) {
            float f = tile[qq * 16 + j][kl];
            s = fmaf(f, f, s);
            u16 hb = f2bf(f);
            u16 lb = f2bf(f - bf2f(hb));
            if (j & 1) { hp[j >> 1] |= (u32)hb << 16; lp[j >> 1] |= (u32)lb << 16; }
            else       { hp[j >> 1]  = hb;            lp[j >> 1]  = lb; }
        }
        s += __shfl_down(s, 1);
        s += __shfl_down(s, 2);
        if (qq == 0) nacc += s;

        size_t o = ((size_t)(kBase + kl) * D + dBase + qq * 16) >> 1;   // uint index
        u32x4 a, b;
        a.x = hp[0]; a.y = hp[1]; a.z = hp[2]; a.w = hp[3];
        b.x = hp[4]; b.y = hp[5]; b.z = hp[6]; b.w = hp[7];
        *(u32x4*)&((u32*)ehT)[o]     = a;
        *(u32x4*)&((u32*)ehT)[o + 4] = b;
        a.x = lp[0]; a.y = lp[1]; a.z = lp[2]; a.w = lp[3];
        b.x = lp[4]; b.y = lp[5]; b.z = lp[6]; b.w = lp[7];
        *(u32x4*)&((u32*)elT)[o]     = a;
        *(u32x4*)&((u32*)elT)[o + 4] = b;
        __syncthreads();
    }
    if (qq == 0) enorm[kBase + kl] = nacc;
}

// ---------------------------------------------------------------------------
// K-MAIN v11: v6's verified 4-phase barrier skeleton + 16x16 frag layout
// (0 bank conflicts) with ONE contained addition: B-fragment register
// double-buffer. Phase p issues ds_read B[p+1] EARLY, waits counted
// lgkmcnt(4) (early reads stay pending), MFMAs B[p]. Every early read of
// region q completes before the same phase-end barrier that protected v6's
// normal read of q -> race-free; ds latency hides under previous MFMAs.
// score(r,k) = enorm[k] - 2*(xh.eh + xh.el + xl.eh)
__global__ __launch_bounds__(512, 2) void dist_argmin_mfma(
        const u16* __restrict__ xh, const u16* __restrict__ xl,
        const u16* __restrict__ ehT, const u16* __restrict__ elT,
        const float* __restrict__ enorm,
        u64* __restrict__ keys) {
    __shared__ u16 lds[2][32768];   // 2 x 64KB

    const int tid  = threadIdx.x;
    const int lane = tid & 63;
    const int wave = tid >> 6;       // 0..7
    const int wm   = wave >> 1;      // row wave 0..3  (64 rows each)
    const int wn   = wave & 1;       // col wave 0..1  (128 cols each)
    const int r = lane & 15, g = lane >> 4;
    const int rowBase = blockIdx.y * 256;
    const int colBase = blockIdx.x * 256;

    f32x4 acc[4][8];
    #pragma unroll
    for (int i = 0; i < 4; ++i)
        #pragma unroll
        for (int j = 0; j < 8; ++j) acc[i][j] = (f32x4)0.f;

    // ---- staging geometry (write side) — unchanged from v6 ----
    const int chunk8 = (((tid & 3) ^ ((tid >> 3) & 3)) * 8);
    const int arow   = tid >> 2;                 // 0..127
    const size_t a0 = (size_t)(rowBase + arow) * D + chunk8;
    const size_t a1 = (size_t)(rowBase + 128 + arow) * D + chunk8;
    const int bmat   = tid >> 8;                 // 0: eh, 1: el
    const int qrow   = (tid & 255) >> 2;         // 0..63
    const int bcol0  = (qrow < 32) ? qrow : (96 + qrow);   // + q*32
    const size_t bq0 = (size_t)(colBase + bcol0) * D + chunk8;
    const u16* bsrc  = bmat ? elT : ehT;

    // read-side k-chunk un-swizzle (u16 offset within a 32-k row)
    const int kx = (g ^ ((r >> 1) & 3)) * 8;

    #define ST_XH0(buf, ks) gl_lds16(&xh[a0 + (ks) * 32], &lds[buf][tid * 8])
    #define ST_XH1(buf, ks) gl_lds16(&xh[a1 + (ks) * 32], &lds[buf][4096 + tid * 8])
    #define ST_XL0(buf, ks) gl_lds16(&xl[a0 + (ks) * 32], &lds[buf][8192 + tid * 8])
    #define ST_XL1(buf, ks) gl_lds16(&xl[a1 + (ks) * 32], &lds[buf][12288 + tid * 8])
    #define ST_B(buf, ks, q) \
        gl_lds16(&bsrc[bq0 + (size_t)(q) * 32 * D + (ks) * 32], \
                 &lds[buf][16384 + (q) * 4096 + tid * 8])

    // ---- prologue: step0 (8 batches, oldest) + step1 first 6 ----
    ST_B(0, 0, 0); ST_XH0(0, 0); ST_B(0, 0, 1); ST_XH1(0, 0);
    ST_B(0, 0, 2); ST_XL0(0, 0); ST_B(0, 0, 3); ST_XL1(0, 0);
    ST_B(1, 1, 0); ST_XH0(1, 1); ST_B(1, 1, 1); ST_XH1(1, 1);
    ST_B(1, 1, 2); ST_XL0(1, 1);

    bf16x8 fah[4], fal[4];
    bf16x8 fbhA[2], fblA[2], fbhB[2], fblB[2];   // B-frag register double buffer

    #define RD_A(Lp)                                                              \
        do { _Pragma("unroll") for (int i_ = 0; i_ < 4; ++i_) {                   \
            fah[i_] = *(const bf16x8*)&(Lp)[((wm * 64 + i_ * 16 + r) * 32) + kx]; \
            fal[i_] = *(const bf16x8*)&(Lp)[8192 + ((wm * 64 + i_ * 16 + r) * 32) + kx]; \
        } } while (0)

    #define RD_B(Lp, p, FH, FL)                                                   \
        do { _Pragma("unroll") for (int jj_ = 0; jj_ < 2; ++jj_) {                \
            const int qr_ = wn * 32 + jj_ * 16 + r;                               \
            (FH)[jj_] = *(const bf16x8*)&(Lp)[16384 + (p) * 4096 + qr_ * 32 + kx];        \
            (FL)[jj_] = *(const bf16x8*)&(Lp)[16384 + (p) * 4096 + 2048 + qr_ * 32 + kx]; \
        } } while (0)

    #define MFMA_PH(p, FH, FL)                                                    \
        do { _Pragma("unroll") for (int i_ = 0; i_ < 4; ++i_) {                   \
            acc[i_][2*(p)]   = __builtin_amdgcn_mfma_f32_16x16x32_bf16(fah[i_], (FH)[0], acc[i_][2*(p)],   0, 0, 0); \
            acc[i_][2*(p)]   = __builtin_amdgcn_mfma_f32_16x16x32_bf16(fah[i_], (FL)[0], acc[i_][2*(p)],   0, 0, 0); \
            acc[i_][2*(p)]   = __builtin_amdgcn_mfma_f32_16x16x32_bf16(fal[i_], (FH)[0], acc[i_][2*(p)],   0, 0, 0); \
            acc[i_][2*(p)+1] = __builtin_amdgcn_mfma_f32_16x16x32_bf16(fah[i_], (FH)[1], acc[i_][2*(p)+1], 0, 0, 0); \
            acc[i_][2*(p)+1] = __builtin_amdgcn_mfma_f32_16x16x32_bf16(fah[i_], (FL)[1], acc[i_][2*(p)+1], 0, 0, 0); \
            acc[i_][2*(p)+1] = __builtin_amdgcn_mfma_f32_16x16x32_bf16(fal[i_], (FH)[1], acc[i_][2*(p)+1], 0, 0, 0); \
        } } while (0)

    #define LGKM4() asm volatile("s_waitcnt lgkmcnt(4)" ::: "memory"); \
                    __builtin_amdgcn_sched_barrier(0)
    #define LGKM0() asm volatile("s_waitcnt lgkmcnt(0)" ::: "memory"); \
                    __builtin_amdgcn_sched_barrier(0)

    #pragma unroll
    for (int ks = 0; ks < 8; ++ks) {
        const int c = ks & 1;
        const u16* L = lds[c];

        // ---- phase 0: gate; read A + B0 + B1(early); stage; MFMA(B0) ----
        if (ks == 7) asm volatile("s_waitcnt vmcnt(0)" ::: "memory");
        else         asm volatile("s_waitcnt vmcnt(6)" ::: "memory");
        __builtin_amdgcn_s_barrier();           // all waves' step-ks loads landed
        __builtin_amdgcn_sched_barrier(0);

        RD_A(L);
        RD_B(L, 0, fbhA, fblA);
        RD_B(L, 1, fbhB, fblB);                 // early: stays pending
        if (ks <= 6) { ST_B(c ^ 1, ks + 1, 3); ST_XL1(c ^ 1, ks + 1); }
        LGKM4();                                // A+B0 done; B1 in flight
        __builtin_amdgcn_s_setprio(1);
        MFMA_PH(0, fbhA, fblA);
        __builtin_amdgcn_s_setprio(0);
        __builtin_amdgcn_s_barrier();           // ph0 reads done -> q0/A free
        __builtin_amdgcn_sched_barrier(0);

        // ---- phase 1: read B2(early); stage q0/XH0; MFMA(B1) ----
        RD_B(L, 2, fbhA, fblA);
        if (ks <= 5) { ST_B(c, ks + 2, 0); ST_XH0(c, ks + 2); }
        LGKM4();                                // B1 done; B2 in flight
        __builtin_amdgcn_s_setprio(1);
        MFMA_PH(1, fbhB, fblB);
        __builtin_amdgcn_s_setprio(0);
        __builtin_amdgcn_s_barrier();
        __builtin_amdgcn_sched_barrier(0);

        // ---- phase 2: read B3(early); stage q1/XH1; MFMA(B2) ----
        RD_B(L, 3, fbhB, fblB);
        if (ks <= 5) { ST_B(c, ks + 2, 1); ST_XH1(c, ks + 2); }
        LGKM4();                                // B2 done; B3 in flight
        __builtin_amdgcn_s_setprio(1);
        MFMA_PH(2, fbhA, fblA);
        __builtin_amdgcn_s_setprio(0);
        __builtin_amdgcn_s_barrier();
        __builtin_amdgcn_sched_barrier(0);

        // ---- phase 3: stage q2/XL0; MFMA(B3) ----
        if (ks <= 5) { ST_B(c, ks + 2, 2); ST_XL0(c, ks + 2); }
        LGKM0();                                // B3 done
        __builtin_amdgcn_s_setprio(1);
        MFMA_PH(3, fbhB, fblB);
        __builtin_amdgcn_s_setprio(0);
        __builtin_amdgcn_s_barrier();
        __builtin_amdgcn_sched_barrier(0);
    }
    #undef MFMA_PH
    #undef RD_A
    #undef RD_B
    #undef LGKM4
    #undef LGKM0
    #undef ST_XH0
    #undef ST_XH1
    #undef ST_XL0
    #undef ST_XL1
    #undef ST_B

    // ---- epilogue: argmin over this block's 256 cols, merge via atomicMin ----
    float en[8];
    #pragma unroll
    for (int j = 0; j < 8; ++j) en[j] = enorm[colBase + wn * 128 + j * 16 + r];

    #pragma unroll
    for (int i = 0; i < 4; ++i) {
        #pragma unroll
        for (int p4 = 0; p4 < 4; ++p4) {
            float best = __builtin_inff();
            int bk = 0;
            #pragma unroll
            for (int j = 0; j < 8; ++j) {
                float s = fmaf(-2.f, acc[i][j][p4], en[j]);
                int ccol = colBase + wn * 128 + j * 16 + r;
                if (s < best) { best = s; bk = ccol; }
            }
            u32 u = __float_as_uint(best);
            u ^= (u >> 31) ? 0xFFFFFFFFu : 0x80000000u;   // monotonic float->uint
            u64 key = ((u64)u << 32) | (u32)bk;
            #pragma unroll
            for (int m = 1; m < 16; m <<= 1) {
                u64 o = __shfl_xor(key, m);
                key = o < key ? o : key;
            }
            if (r == 0)
                atomicMin(&keys[rowBase + wm * 64 + i * 16 + g * 4 + p4], key);
        }
    }
}

// ---------------------------------------------------------------------------
// K4: fused postprocess — per row: quantize gather + q_out write + loss
// partial + EMA scatter into transposed acc_t[K][D] (coalesced atomics).
__global__ void postprocess_kernel(const float* __restrict__ x,
                                   const u16* __restrict__ ehT,
                                   const u16* __restrict__ elT,
                                   const u64* __restrict__ keys,
                                   float* __restrict__ q_out,
                                   float* __restrict__ loss_out,
                                   float* __restrict__ acc_t,
                                   float* __restrict__ ncs_out) {
    const int w    = threadIdx.x >> 6;
    const int lane = threadIdx.x & 63;
    const int r    = blockIdx.x * 4 + w;
    const u32 k = (u32)keys[r];

    float4 xv = *(const float4*)&x[(size_t)r * D + lane * 4];
    size_t uo = ((size_t)k * D >> 1) + lane * 2;
    u32x2 hp = *(const u32x2*)&((const u32*)ehT)[uo];
    u32x2 lp = *(const u32x2*)&((const u32*)elT)[uo];
    float q0 = __uint_as_float(hp.x << 16)         + __uint_as_float(lp.x << 16);
    float q1 = __uint_as_float(hp.x & 0xFFFF0000u) + __uint_as_float(lp.x & 0xFFFF0000u);
    float q2 = __uint_as_float(hp.y << 16)         + __uint_as_float(lp.y << 16);
    float q3 = __uint_as_float(hp.y & 0xFFFF0000u) + __uint_as_float(lp.y & 0xFFFF0000u);
    *(float4*)&q_out[(size_t)r * D + lane * 4] = make_float4(q0, q1, q2, q3);

    float* dst = &acc_t[(size_t)k * D + lane * 4];
    atomicAdd(dst + 0, xv.x);
    atomicAdd(dst + 1, xv.y);
    atomicAdd(dst + 2, xv.z);
    atomicAdd(dst + 3, xv.w);
    if (lane == 0) atomicAdd(&ncs_out[k], OMD);

    float d0 = q0 - xv.x, d1 = q1 - xv.y, d2 = q2 - xv.z, d3 = q3 - xv.w;
    float lsum = fmaf(d0, d0, fmaf(d1, d1, fmaf(d2, d2, d3 * d3)));
    #pragma unroll
    for (int off = 32; off > 0; off >>= 1) lsum += __shfl_down(lsum, off);
    __shared__ float wsum[4];
    if (lane == 0) wsum[w] = lsum;
    __syncthreads();
    if (threadIdx.x == 0) {
        float s = wsum[0] + wsum[1] + wsum[2] + wsum[3];
        atomicAdd(loss_out, s * (1.0f / ((float)NROWS * (float)D)));
    }
}

// K6: fused finalize — transpose acc_t[K][D] -> nea_out[D][K] combined with
// EMA (0.99*embed_avg + 0.01*acc) AND new_embed = nea/cs in one pass.
// n is re-derived per block from cluster_size (32KB, L2-resident).
__global__ void ema_finalize_kernel(const float* __restrict__ embed_avg,
                                    const float* __restrict__ acc_t,
                                    const float* __restrict__ ncs_out,
                                    const float* __restrict__ cluster_size,
                                    float* __restrict__ nea_out,
                                    float* __restrict__ ne_out) {
    __shared__ float tile[64][68];   // [k][d]
    __shared__ float wsums[4];
    const int kBase = blockIdx.x * 64;   // K/64 = 128
    const int dBase = blockIdx.y * 64;   // D/64 = 4
    const int t = threadIdx.x;

    // per-block cssum reduce (stride-256 coalesced)
    float cs_part = 0.f;
    #pragma unroll
    for (int j = 0; j < K / 256; ++j) cs_part += cluster_size[j * 256 + t];
    #pragma unroll
    for (int off = 32; off > 0; off >>= 1) cs_part += __shfl_down(cs_part, off);
    if ((t & 63) == 0) wsums[t >> 6] = cs_part;

    {
        const int kl = t >> 2, q = t & 3;
        #pragma unroll
        for (int i = 0; i < 4; ++i) {
            int dd = q * 16 + i * 4;
            float4 v = *(const float4*)&acc_t[(size_t)(kBase + kl) * D + dBase + dd];
            tile[kl][dd + 0] = v.x; tile[kl][dd + 1] = v.y;
            tile[kl][dd + 2] = v.z; tile[kl][dd + 3] = v.w;
        }
    }
    __syncthreads();
    const float cssum = wsums[0] + wsums[1] + wsums[2] + wsums[3];
    const float n = DECAY * cssum + OMD * (float)NROWS;
    const float inv_na = 1.0f / (n + (float)K * EPSF);
    const int dl = t >> 2, q = t & 3;
    #pragma unroll
    for (int i = 0; i < 4; ++i) {
        int kk = q * 16 + i * 4;
        size_t o = (size_t)(dBase + dl) * K + kBase + kk;
        float4 ea = *(const float4*)&embed_avg[o];
        float4 nea, ne;
        #pragma unroll
        for (int c = 0; c < 4; ++c) {
            float v  = DECAY * ((const float*)&ea)[c] + OMD * tile[kk + c][dl];
            float cs = (ncs_out[kBase + kk + c] + EPSF) * inv_na * n;
            ((float*)&nea)[c] = v;
            ((float*)&ne)[c]  = v / cs;
        }
        *(float4*)&nea_out[o] = nea;
        *(float4*)&ne_out[o]  = ne;
    }
}

// ---------------------------------------------------------------------------
extern "C" void kernel_launch(void* const* d_in, const int* in_sizes, int n_in,
                              void* d_out, int out_size, void* d_ws, size_t ws_size,
                              hipStream_t stream) {
    (void)in_sizes; (void)n_in; (void)out_size; (void)ws_size;
    const float* x            = (const float*)d_in[0];
    const float* embed        = (const float*)d_in[1];
    const float* cluster_size = (const float*)d_in[2];
    const float* embed_avg    = (const float*)d_in[3];
    float* out = (float*)d_out;

    char* ws = (char*)d_ws;
    u64*   keys  = (u64*)(ws + WS_KEYS);
    float* enorm = (float*)(ws + WS_ENORM);
    u16*   xh    = (u16*)(ws + WS_XH);
    u16*   xl    = (u16*)(ws + WS_XL);
    u16*   ehT   = (u16*)(ws + WS_EHT);
    u16*   elT   = (u16*)(ws + WS_ELT);
    float* acc_t = (float*)(ws + WS_XH);   // aliases xh: dead after main kernel

    float* q_out    = out + OUT_Q;
    float* loss_out = out + OUT_LOSS;
    float* ne_out   = out + OUT_NE;
    float* ncs_out  = out + OUT_NCS;
    float* nea_out  = out + OUT_NEA;

    // One fused pre-kernel: transpose/split/enorm + keys init + ncs init +
    // loss zero + x split.
    pre_kernel<<<dim3(176 + NROWS * D / 4 / 256), dim3(256), 0, stream>>>(
        x, embed, cluster_size, xh, xl, ehT, elT, enorm, keys, ncs_out, loss_out);

    dist_argmin_mfma<<<dim3(K / 256, NROWS / 256), dim3(512), 0, stream>>>(
        xh, xl, ehT, elT, enorm, keys);

    // xh is dead now; reuse it as the transposed EMA accumulator
    hipMemsetAsync(acc_t, 0, (size_t)K * D * 4, stream);
    postprocess_kernel<<<dim3(NROWS / 4), dim3(256), 0, stream>>>(
        x, ehT, elT, keys, q_out, loss_out, acc_t, ncs_out);
    ema_finalize_kernel<<<dim3(K / 64, D / 64), dim3(256), 0, stream>>>(
        embed_avg, acc_t, ncs_out, cluster_size, nea_out, ne_out);
}